// Round 4
// baseline (261.696 us; speedup 1.0000x reference)
//
#include <hip/hip_runtime.h>
#include <stdint.h>

// ---------------------------------------------------------------------------
// GCN block: 3 x [ h = leaky_relu(in @ W);  out = adj@h + h ]   (I folded OUT)
// B=64, N=4096, D=16.  GEMM M=4096 x C=1024 x K=4096, fp8 e4m3 MX-scaled
// mfma_scale_16x16x128 (unit scales), fp32 accum over FULL K per block.
// Round 10: r9 dbuf was neutral (2 blocks/CU already hid latency) and the
// pipeline spent >100us outside the gemms.  Restructure:
//  - 256 blocks, 128x128 tile, full K (no ks split), 1 block/CU (96KB LDS).
//  - K-loop: TRIPLE-buffered LDS, counted s_waitcnt vmcnt(8) + raw s_barrier,
//    one barrier/iter, stages 2-deep in flight (T3+T4).  Buffer parity makes
//    the WAR across one barrier safe: stage(it+2) targets buf[(it+2)%3] =
//    buf[(it-1)%3], whose readers all passed the preceding barrier.
//  - Epilogue fusion: the linear mixes channels only within 16-wide groups,
//    all inside the tile.  mode 0: u = acc/4096 + hnc; h' = leaky(u@W');
//    write hb8' (fp8 [c][n] via swizzled LDS transpose) + hnc' (bf16 [n][c]).
//    mode 1: out = u in fp32 (b,n,d).  linear_fuse + add_out kernels GONE.
// 4 launches: prep, gemm(W1), gemm(W2), gemm(final).
// ws: adj8 16MB | hb8_a 4MB | hb8_b 4MB | hnc 8MB = 32MB
// ---------------------------------------------------------------------------

typedef float  f32x4  __attribute__((ext_vector_type(4)));
typedef unsigned short ushort8 __attribute__((ext_vector_type(8)));
typedef int    i32x4  __attribute__((ext_vector_type(4)));
typedef int    i32x8  __attribute__((ext_vector_type(8)));

typedef __attribute__((address_space(1))) void* as1p;
typedef __attribute__((address_space(3))) void* as3p;
#define GLOAD_LDS16(G, L) \
  __builtin_amdgcn_global_load_lds((as1p)(G), (as3p)(L), 16, 0, 0)

#define ADJ_SCALE 4096.0f
#define ADJ_DESCALE (1.0f / 4096.0f)
#define SCALE_ONE 0x7f7f7f7f  // e8m0 exponent 127 = 2^0 = 1.0 in every byte

__device__ __forceinline__ unsigned short f2bf(float f) {
  unsigned u = __float_as_uint(f);
  u += 0x7fffu + ((u >> 16) & 1u);  // RNE
  return (unsigned short)(u >> 16);
}
__device__ __forceinline__ float bf2f(unsigned short u) {
  return __uint_as_float(((unsigned)u) << 16);
}
// pack 4 fp32 -> 4 fp8 e4m3 bytes (RNE, saturating)
__device__ __forceinline__ int pk4_fp8(float a, float b, float c, float d) {
  int v = __builtin_amdgcn_cvt_pk_fp8_f32(a, b, 0, false);   // bytes 0,1
  v = __builtin_amdgcn_cvt_pk_fp8_f32(c, d, v, true);        // bytes 2,3
  return v;
}

// ---------------------------------------------------------------------------
// prep: role-split fusion of two independent memory-bound kernels.
//   bid <  1024 : layer-0 linear  h0 = leaky(x @ W0), tile 64n x 64c
//   bid >= 1024 : adj8 = e4m3(adj * 4096), 1 thread = 16 elements
// ---------------------------------------------------------------------------
__global__ void prep(const float* __restrict__ adj,
                     unsigned char* __restrict__ a8,
                     const float* __restrict__ x,
                     const float* __restrict__ W,
                     unsigned char* __restrict__ hb8,
                     unsigned short* __restrict__ hnc_out) {
  __shared__ float xs[64 * 65];
  __shared__ unsigned short ht[64 * 72];
  int bid = blockIdx.x;

  if (bid >= 1024) {
    // ---- adj quantize part ----
    size_t base = ((size_t)(bid - 1024) * 256 + threadIdx.x) * 16;
    const float4* src = (const float4*)(adj + base);
    float4 q0 = src[0], q1 = src[1], q2 = src[2], q3 = src[3];
    int4 o;
    o.x = pk4_fp8(q0.x * ADJ_SCALE, q0.y * ADJ_SCALE, q0.z * ADJ_SCALE, q0.w * ADJ_SCALE);
    o.y = pk4_fp8(q1.x * ADJ_SCALE, q1.y * ADJ_SCALE, q1.z * ADJ_SCALE, q1.w * ADJ_SCALE);
    o.z = pk4_fp8(q2.x * ADJ_SCALE, q2.y * ADJ_SCALE, q2.z * ADJ_SCALE, q2.w * ADJ_SCALE);
    o.w = pk4_fp8(q3.x * ADJ_SCALE, q3.y * ADJ_SCALE, q3.z * ADJ_SCALE, q3.w * ADJ_SCALE);
    *(int4*)(a8 + base) = o;
    return;
  }

  // ---- layer-0 linear part ----
  int n0 = (bid & 63) * 64, c0 = (bid >> 6) * 64;

  for (int i = threadIdx.x; i < 1024; i += 256) {
    int bs = i >> 8, rem = i & 255, nr = rem >> 2, d4 = rem & 3;
    float4 v = *(const float4*)(
        x + ((size_t)(c0 / 16 + bs) * 4096 + n0 + nr) * 16 + d4 * 4);
    float* dst = xs + nr * 65 + bs * 16 + d4 * 4;
    dst[0] = v.x; dst[1] = v.y; dst[2] = v.z; dst[3] = v.w;
  }
  __syncthreads();

  int n_l = threadIdx.x & 63, b_l = threadIdx.x >> 6;   // b_l 0..3
  float xv[16];
#pragma unroll
  for (int d = 0; d < 16; ++d) xv[d] = xs[n_l * 65 + b_l * 16 + d];
  float accv[16];
#pragma unroll
  for (int e = 0; e < 16; ++e) accv[e] = 0.f;
#pragma unroll
  for (int d = 0; d < 16; ++d)
#pragma unroll
    for (int e = 0; e < 16; ++e) accv[e] += xv[d] * W[d * 16 + e];

  ushort8 h0, h1;
#pragma unroll
  for (int e = 0; e < 16; ++e) {
    float a = accv[e] > 0.f ? accv[e] : 0.2f * accv[e];
    unsigned short hv = f2bf(a);
    ht[(b_l * 16 + e) * 72 + n_l] = hv;
    if (e < 8) h0[e] = hv; else h1[e - 8] = hv;
  }
  unsigned short* ho = hnc_out + (size_t)(n0 + n_l) * 1024 + c0 + b_l * 16;
  *(ushort8*)(ho)     = h0;
  *(ushort8*)(ho + 8) = h1;
  __syncthreads();

  for (int i = threadIdx.x; i < 512; i += 256) {
    int row = i >> 3, ch = i & 7;
    const unsigned short* s = ht + row * 72 + ch * 8;
    int2 v;
    v.x = pk4_fp8(bf2f(s[0]), bf2f(s[1]), bf2f(s[2]), bf2f(s[3]));
    v.y = pk4_fp8(bf2f(s[4]), bf2f(s[5]), bf2f(s[6]), bf2f(s[7]));
    *(int2*)(hb8 + (size_t)(c0 + row) * 4096 + n0 + ch * 8) = v;
  }
}

// ---------------------------------------------------------------------------
// gemm + fused next-layer linear (mode 0) or final output (mode 1).
// p[n][c] = (adj8[n0..][k] * hb8[c0..][k]) / 4096, full K per block.
// Grid 256 = 4mth x 8ct x 8xcd, 4 waves 2x2, wave tile 64x64.
// K-loop: triple-buffered gload_lds staging, XOR chunk swizzle
// phys = logical ^ (row&7), counted vmcnt(8) + raw s_barrier (1/iter).
// Epilogue (all in the 96KB smem, aliased after the loop):
//   deposit acc fp32 -> u_lds[128][128] (XOR-16 col swizzle, conflict-free)
//   mode 0: u = acc/4096 + hnc; h' = leaky(u @ Wn) per 16-group;
//           hnc <- h' (bf16), ht <- h' transposed (chunk-XOR swizzle),
//           hb8o <- fp8(ht) rows [c][n].
//   mode 1: out[(c>>4)*65536 + n*16 + (c&15)] = u  (fp32, coalesced).
// ---------------------------------------------------------------------------
__global__ __launch_bounds__(256, 1)
void gemm_f8(const unsigned char* __restrict__ A,
             const unsigned char* __restrict__ B8,
             const float* __restrict__ Wn,
             unsigned short* __restrict__ hnc,
             unsigned char* __restrict__ hb8o,
             float* __restrict__ out,
             int mode) {
  const int K = 4096;
  __shared__ unsigned char smem[98304];          // 3x16KB A | 3x16KB B
  unsigned char* a_s[3] = {smem, smem + 16384, smem + 32768};
  unsigned char* b_s[3] = {smem + 49152, smem + 65536, smem + 81920};

  int tid = threadIdx.x, wave = tid >> 6, lane = tid & 63;

  int lin = blockIdx.x;                          // 256 blocks
  int xcd = lin & 7, g = lin >> 3;
  int mth = g & 3, ct = g >> 2;                  // ct 0..7
  int mt = mth * 8 + xcd;                        // 0..31
  int n0 = mt * 128, c0 = ct * 128;

  // staging: wave w covers rows w*32..w*32+31 (4 insts each operand)
  int l8 = lane >> 3, lc = lane & 7;
  int swc = lc ^ l8;                 // logical chunk fetched into phys lc
  const unsigned char* gA[4];
  const unsigned char* gB[4];
#pragma unroll
  for (int j = 0; j < 4; ++j) {
    int r = wave * 32 + j * 8 + l8;
    gA[j] = A  + (size_t)(n0 + r) * K + swc * 16;
    gB[j] = B8 + (size_t)(c0 + r) * K + swc * 16;
  }

  int i16 = lane & 15, q = lane >> 4;
  int wm = wave >> 1, wn = wave & 1;
  int sw7 = i16 & 7;
  int pc0 = ((2 * q) ^ sw7) * 16;        // phys offset of logical chunk 2q
  int pc1 = ((2 * q + 1) ^ sw7) * 16;    // phys offset of logical chunk 2q+1

#define STAGE(buf, it)                                                \
  do {                                                                \
    int k0_ = (it) * 128;                                             \
    _Pragma("unroll")                                                 \
    for (int j = 0; j < 4; ++j) {                                     \
      GLOAD_LDS16(gA[j] + k0_, a_s[buf] + (wave * 32 + j * 8) * 128); \
      GLOAD_LDS16(gB[j] + k0_, b_s[buf] + (wave * 32 + j * 8) * 128); \
    }                                                                 \
  } while (0)

#define COMPUTE(buf)                                                  \
  do {                                                                \
    i32x8 bv[4];                                                      \
    _Pragma("unroll")                                                 \
    for (int u = 0; u < 4; ++u) {                                     \
      const unsigned char* bp = b_s[buf] + (wn * 64 + u * 16 + i16) * 128; \
      i32x4 blo = *(const i32x4*)(bp + pc0);                          \
      i32x4 bhi = *(const i32x4*)(bp + pc1);                          \
      bv[u] = __builtin_shufflevector(blo, bhi, 0, 1, 2, 3, 4, 5, 6, 7); \
    }                                                                 \
    _Pragma("unroll")                                                 \
    for (int t = 0; t < 4; ++t) {                                     \
      const unsigned char* ap = a_s[buf] + (wm * 64 + t * 16 + i16) * 128; \
      i32x4 alo = *(const i32x4*)(ap + pc0);                          \
      i32x4 ahi = *(const i32x4*)(ap + pc1);                          \
      i32x8 av = __builtin_shufflevector(alo, ahi, 0, 1, 2, 3, 4, 5, 6, 7); \
      _Pragma("unroll")                                               \
      for (int u = 0; u < 4; ++u)                                     \
        acc[t][u] = __builtin_amdgcn_mfma_scale_f32_16x16x128_f8f6f4( \
            av, bv[u], acc[t][u], 0, 0, 0, SCALE_ONE, 0, SCALE_ONE);  \
    }                                                                 \
  } while (0)

#define WAITVM8() asm volatile("s_waitcnt vmcnt(8)" ::: "memory")
#define WAITVM0() asm volatile("s_waitcnt vmcnt(0)" ::: "memory")
#define BARX() do { __builtin_amdgcn_s_barrier(); \
                    asm volatile("" ::: "memory"); } while (0)

  f32x4 acc[4][4] = {};

  // prologue: two stages in flight
  STAGE(0, 0);
  STAGE(1, 1);

  // phases 0..29: WAIT(stage it done) -> barrier -> stage(it+2) -> compute(it)
  // stage(it+2) targets buf[(it+2)%3] = buf[(it-1)%3]; its readers (compute
  // it-1) all passed the barrier above -> no WAR race.
  for (int itb = 0; itb < 30; itb += 3) {
    WAITVM8(); BARX(); STAGE(2, itb + 2); COMPUTE(0);
    WAITVM8(); BARX(); STAGE(0, itb + 3); COMPUTE(1);
    WAITVM8(); BARX(); STAGE(1, itb + 4); COMPUTE(2);
  }
  // note: itb=27 stages it 29,30,31; loop stages up to 31 exactly (29+2).
  WAITVM8(); BARX(); COMPUTE(0);                 // it = 30
  WAITVM0(); BARX(); COMPUTE(1);                 // it = 31

#undef STAGE
#undef COMPUTE
#undef WAITVM8
#undef WAITVM0
#undef BARX

  // -------------------------------------------------------------------------
  // epilogue
  // -------------------------------------------------------------------------
  __syncthreads();                   // all compute reads done; alias smem
  float* u_lds = (float*)smem;                       // 64 KB [128][128]
  unsigned short* ht = (unsigned short*)(smem + 65536);  // 32 KB [128][128]

  // deposit raw acc fp32 with XOR-16 column swizzle (2-way max -> free)
#pragma unroll
  for (int t = 0; t < 4; ++t)
#pragma unroll
    for (int u = 0; u < 4; ++u)
#pragma unroll
      for (int i = 0; i < 4; ++i) {
        int n_l = wm * 64 + t * 16 + q * 4 + i;
        int c_l = wn * 64 + u * 16 + i16;
        u_lds[n_l * 128 + (c_l ^ (((n_l >> 2) & 1) << 4))] = acc[t][u][i];
      }
  __syncthreads();

  if (mode == 0) {
    for (int s = 0; s < 4; ++s) {
      int item = s * 256 + tid;                  // 1024 (n, group) items
      int n_l = item & 127, gi = item >> 7;      // gi 0..7
      int pg = gi ^ ((n_l >> 2) & 1);
      const float* up = u_lds + n_l * 128 + pg * 16;
      size_t gb = (size_t)(n0 + n_l) * 1024 + c0 + gi * 16;
      ushort8 hn0 = *(const ushort8*)(hnc + gb);
      ushort8 hn1 = *(const ushort8*)(hnc + gb + 8);
      float ud[16];
#pragma unroll
      for (int d = 0; d < 8; ++d) {
        ud[d]     = up[d]     * ADJ_DESCALE + bf2f(hn0[d]);
        ud[d + 8] = up[d + 8] * ADJ_DESCALE + bf2f(hn1[d]);
      }
      float hv[16];
#pragma unroll
      for (int e = 0; e < 16; ++e) hv[e] = 0.f;
#pragma unroll
      for (int d = 0; d < 16; ++d)
#pragma unroll
        for (int e = 0; e < 16; ++e) hv[e] += ud[d] * Wn[d * 16 + e];
      ushort8 o0, o1;
#pragma unroll
      for (int e = 0; e < 16; ++e) {
        float a = hv[e] > 0.f ? hv[e] : 0.2f * hv[e];
        unsigned short hb = f2bf(a);
        if (e < 8) o0[e] = hb; else o1[e - 8] = hb;
        int cr = gi * 16 + e;                    // transposed stash, swizzled
        ht[cr * 128 + (((n_l >> 3) ^ (cr & 15)) << 3) + (n_l & 7)] = hb;
      }
      *(ushort8*)(hnc + gb)     = o0;            // h' identity term (in-place)
      *(ushort8*)(hnc + gb + 8) = o1;
    }
    __syncthreads();
    // transposed fp8 store: hb8o[c][n]
    for (int s = 0; s < 8; ++s) {
      int item = s * 256 + tid;                  // 2048 = 128c x 16 chunks
      int c_l = item >> 4, n8 = item & 15;
      const unsigned short* hp = ht + c_l * 128 + ((n8 ^ (c_l & 15)) << 3);
      int2 v;
      v.x = pk4_fp8(bf2f(hp[0]), bf2f(hp[1]), bf2f(hp[2]), bf2f(hp[3]));
      v.y = pk4_fp8(bf2f(hp[4]), bf2f(hp[5]), bf2f(hp[6]), bf2f(hp[7]));
      *(int2*)(hb8o + (size_t)(c0 + c_l) * 4096 + n0 + n8 * 8) = v;
    }
  } else {
    // final: out fp32 (b,n,d), b = c/16, d = c&15
    for (int s = 0; s < 4; ++s) {
      int item = s * 256 + tid;
      int n_l = item & 127, gi = item >> 7;
      int pg = gi ^ ((n_l >> 2) & 1);
      const float* up = u_lds + n_l * 128 + pg * 16;
      size_t gb = (size_t)(n0 + n_l) * 1024 + c0 + gi * 16;
      ushort8 hn0 = *(const ushort8*)(hnc + gb);
      ushort8 hn1 = *(const ushort8*)(hnc + gb + 8);
      float v[16];
#pragma unroll
      for (int d = 0; d < 8; ++d) {
        v[d]     = up[d]     * ADJ_DESCALE + bf2f(hn0[d]);
        v[d + 8] = up[d + 8] * ADJ_DESCALE + bf2f(hn1[d]);
      }
      int bb = (c0 >> 4) + gi;
      float* op = out + (size_t)bb * 65536 + (size_t)(n0 + n_l) * 16;
      *(float4*)(op)      = float4{v[0],  v[1],  v[2],  v[3]};
      *(float4*)(op + 4)  = float4{v[4],  v[5],  v[6],  v[7]};
      *(float4*)(op + 8)  = float4{v[8],  v[9],  v[10], v[11]};
      *(float4*)(op + 12) = float4{v[12], v[13], v[14], v[15]};
    }
  }
}

// ---------------------------------------------------------------------------
extern "C" void kernel_launch(void* const* d_in, const int* in_sizes, int n_in,
                              void* d_out, int out_size, void* d_ws, size_t ws_size,
                              hipStream_t stream) {
  const float* x   = (const float*)d_in[0];
  const float* adj = (const float*)d_in[1];
  // d_in[2] = Identity (handled as the +h_nc term)
  const float* W0  = (const float*)d_in[3];
  const float* W1  = (const float*)d_in[4];
  const float* W2  = (const float*)d_in[5];
  float* out = (float*)d_out;

  char* ws = (char*)d_ws;
  unsigned char*  adj8  = (unsigned char*)ws;                  // 16 MiB
  unsigned char*  hb8_a = (unsigned char*)(ws + 16777216);     //  4 MiB
  unsigned char*  hb8_b = (unsigned char*)(ws + 20971520);     //  4 MiB
  unsigned short* hnc   = (unsigned short*)(ws + 25165824);    //  8 MiB

  // layer 0 linear + adj quantize fused (independent, both memory-bound)
  prep<<<5120, 256, 0, stream>>>(adj, adj8, x, W0, hb8_a, hnc);
  // layer 0 gemm + fused layer-1 linear
  gemm_f8<<<256, 256, 0, stream>>>(adj8, hb8_a, W1, hnc, hb8_b, out, 0);
  // layer 1 gemm + fused layer-2 linear
  gemm_f8<<<256, 256, 0, stream>>>(adj8, hb8_b, W2, hnc, hb8_a, out, 0);
  // layer 2 gemm + final output
  gemm_f8<<<256, 256, 0, stream>>>(adj8, hb8_a, (const float*)nullptr,
                                   hnc, (unsigned char*)nullptr, out, 1);
}

// Round 6
// 246.801 us; speedup vs baseline: 1.0604x; 1.0604x over previous
//
#include <hip/hip_runtime.h>
#include <stdint.h>

// ---------------------------------------------------------------------------
// GCN block: 3 x [ h = leaky_relu(in @ W);  out = adj@h + h ]   (I folded OUT)
// B=64, N=4096, D=16.  GEMM M=4096 x C=1024 x K=4096 in FP8 e4m3, fp32 accum,
// MX-scaled mfma_scale_16x16x128 with unit scales (2.26x fp8 pipe rate).
// Round 12 = r11 resubmit (bench infra failed; kernel re-audited: vmcnt
// ledger balanced, barriers uniform, WAR parity safe).
// r10 post-mortem: 1 block/CU removed all TLP (Occ 10%, VALU 33% exposed),
// gemm 47.7us.  r9's __syncthreads drains vmcnt(0) -> dbuf never pipelined.
// This round: proven r7 geometry (ks=2, 512 blocks, 2 blocks/CU, XOR
// swizzle, separate linear/add kernels) + the REAL pipeline:
//   counted s_waitcnt vmcnt(8) + raw s_barrier, dbuf, stage(it+2) issued
//   post-compute-barrier, drained 2 iters later.  ~900cyc load latency
//   hides under compute + the other block.  s_setprio(1) around MFMA
//   (2 independent blocks/CU = role diversity, m191 regime).
// ws: adj8 16MB | hb8 4MB | h_nc 8MB | p0 8MB | p1 8MB = 44MB
// ---------------------------------------------------------------------------

typedef float  f32x4  __attribute__((ext_vector_type(4)));
typedef unsigned short ushort8 __attribute__((ext_vector_type(8)));
typedef int    i32x4  __attribute__((ext_vector_type(4)));
typedef int    i32x8  __attribute__((ext_vector_type(8)));

typedef __attribute__((address_space(1))) void* as1p;
typedef __attribute__((address_space(3))) void* as3p;
#define GLOAD_LDS16(G, L) \
  __builtin_amdgcn_global_load_lds((as1p)(G), (as3p)(L), 16, 0, 0)

#define P_ELEMS 4194304       // elems per partial buffer (4096*1024)
#define ADJ_SCALE 4096.0f
#define ADJ_DESCALE (1.0f / 4096.0f)
#define SCALE_ONE 0x7f7f7f7f  // e8m0 exponent 127 = 2^0 = 1.0 in every byte

__device__ __forceinline__ unsigned short f2bf(float f) {
  unsigned u = __float_as_uint(f);
  u += 0x7fffu + ((u >> 16) & 1u);  // RNE
  return (unsigned short)(u >> 16);
}
__device__ __forceinline__ float bf2f(unsigned short u) {
  return __uint_as_float(((unsigned)u) << 16);
}
// pack 4 fp32 -> 4 fp8 e4m3 bytes (RNE, saturating)
__device__ __forceinline__ int pk4_fp8(float a, float b, float c, float d) {
  int v = __builtin_amdgcn_cvt_pk_fp8_f32(a, b, 0, false);   // bytes 0,1
  v = __builtin_amdgcn_cvt_pk_fp8_f32(c, d, v, true);        // bytes 2,3
  return v;
}

// ---------------------------------------------------------------------------
// prep: role-split fusion of two independent memory-bound kernels.
//   bid <  1024 : layer-0 linear  h0 = leaky(x @ W0), tile 64n x 64c
//   bid >= 1024 : adj8 = e4m3(adj * 4096), 1 thread = 16 elements
// ---------------------------------------------------------------------------
__global__ void prep(const float* __restrict__ adj,
                     unsigned char* __restrict__ a8,
                     const float* __restrict__ x,
                     const float* __restrict__ W,
                     unsigned char* __restrict__ hb8,
                     unsigned short* __restrict__ hnc_out) {
  __shared__ float xs[64 * 65];
  __shared__ unsigned short ht[64 * 72];
  int bid = blockIdx.x;

  if (bid >= 1024) {
    // ---- adj quantize part ----
    size_t base = ((size_t)(bid - 1024) * 256 + threadIdx.x) * 16;
    const float4* src = (const float4*)(adj + base);
    float4 q0 = src[0], q1 = src[1], q2 = src[2], q3 = src[3];
    int4 o;
    o.x = pk4_fp8(q0.x * ADJ_SCALE, q0.y * ADJ_SCALE, q0.z * ADJ_SCALE, q0.w * ADJ_SCALE);
    o.y = pk4_fp8(q1.x * ADJ_SCALE, q1.y * ADJ_SCALE, q1.z * ADJ_SCALE, q1.w * ADJ_SCALE);
    o.z = pk4_fp8(q2.x * ADJ_SCALE, q2.y * ADJ_SCALE, q2.z * ADJ_SCALE, q2.w * ADJ_SCALE);
    o.w = pk4_fp8(q3.x * ADJ_SCALE, q3.y * ADJ_SCALE, q3.z * ADJ_SCALE, q3.w * ADJ_SCALE);
    *(int4*)(a8 + base) = o;
    return;
  }

  // ---- layer-0 linear part ----
  int n0 = (bid & 63) * 64, c0 = (bid >> 6) * 64;

  for (int i = threadIdx.x; i < 1024; i += 256) {
    int bs = i >> 8, rem = i & 255, nr = rem >> 2, d4 = rem & 3;
    float4 v = *(const float4*)(
        x + ((size_t)(c0 / 16 + bs) * 4096 + n0 + nr) * 16 + d4 * 4);
    float* dst = xs + nr * 65 + bs * 16 + d4 * 4;
    dst[0] = v.x; dst[1] = v.y; dst[2] = v.z; dst[3] = v.w;
  }
  __syncthreads();

  int n_l = threadIdx.x & 63, b_l = threadIdx.x >> 6;   // b_l 0..3
  float xv[16];
#pragma unroll
  for (int d = 0; d < 16; ++d) xv[d] = xs[n_l * 65 + b_l * 16 + d];
  float accv[16];
#pragma unroll
  for (int e = 0; e < 16; ++e) accv[e] = 0.f;
#pragma unroll
  for (int d = 0; d < 16; ++d)
#pragma unroll
    for (int e = 0; e < 16; ++e) accv[e] += xv[d] * W[d * 16 + e];

  ushort8 h0, h1;
#pragma unroll
  for (int e = 0; e < 16; ++e) {
    float a = accv[e] > 0.f ? accv[e] : 0.2f * accv[e];
    unsigned short hv = f2bf(a);
    ht[(b_l * 16 + e) * 72 + n_l] = hv;
    if (e < 8) h0[e] = hv; else h1[e - 8] = hv;
  }
  unsigned short* ho = hnc_out + (size_t)(n0 + n_l) * 1024 + c0 + b_l * 16;
  *(ushort8*)(ho)     = h0;
  *(ushort8*)(ho + 8) = h1;
  __syncthreads();

  for (int i = threadIdx.x; i < 512; i += 256) {
    int row = i >> 3, ch = i & 7;
    const unsigned short* s = ht + row * 72 + ch * 8;
    int2 v;
    v.x = pk4_fp8(bf2f(s[0]), bf2f(s[1]), bf2f(s[2]), bf2f(s[3]));
    v.y = pk4_fp8(bf2f(s[4]), bf2f(s[5]), bf2f(s[6]), bf2f(s[7]));
    *(int2*)(hb8 + (size_t)(c0 + row) * 4096 + n0 + ch * 8) = v;
  }
}

// ---------------------------------------------------------------------------
// linear layers 1,2: u = p0 + p1 + h_nc (bf16); h = leaky_relu(u @ W);
// writes hb8 fp8 [c][n] (GEMM B operand, via LDS transpose) and h_nc bf16
// [n][c] (identity term for consumers).  Tile 64n x 64c, grid (64,16).
// ---------------------------------------------------------------------------
__global__ void linear_fuse(const unsigned short* __restrict__ pp,
                            const unsigned short* __restrict__ hnc_in,
                            const float* __restrict__ W,
                            unsigned char* __restrict__ hb8,
                            unsigned short* __restrict__ hnc_out) {
  __shared__ float xs[64 * 65];
  __shared__ unsigned short ht[64 * 72];
  int n0 = blockIdx.x * 64, c0 = blockIdx.y * 64;

  for (int i = threadIdx.x; i < 512; i += 256) {
    int row = i >> 3, ch = i & 7;
    size_t g = (size_t)(n0 + row) * 1024 + c0 + ch * 8;
    ushort8 a = *(const ushort8*)(pp + g);
    ushort8 b = *(const ushort8*)(pp + P_ELEMS + g);
    ushort8 c = *(const ushort8*)(hnc_in + g);
    float* dst = xs + row * 65 + ch * 8;
#pragma unroll
    for (int j = 0; j < 8; ++j) dst[j] = bf2f(a[j]) + bf2f(b[j]) + bf2f(c[j]);
  }
  __syncthreads();

  int n_l = threadIdx.x & 63, b_l = threadIdx.x >> 6;
  float xv[16];
#pragma unroll
  for (int d = 0; d < 16; ++d) xv[d] = xs[n_l * 65 + b_l * 16 + d];
  float accv[16];
#pragma unroll
  for (int e = 0; e < 16; ++e) accv[e] = 0.f;
#pragma unroll
  for (int d = 0; d < 16; ++d)
#pragma unroll
    for (int e = 0; e < 16; ++e) accv[e] += xv[d] * W[d * 16 + e];

  ushort8 h0, h1;
#pragma unroll
  for (int e = 0; e < 16; ++e) {
    float a = accv[e] > 0.f ? accv[e] : 0.2f * accv[e];
    unsigned short hv = f2bf(a);
    ht[(b_l * 16 + e) * 72 + n_l] = hv;
    if (e < 8) h0[e] = hv; else h1[e - 8] = hv;
  }
  unsigned short* ho = hnc_out + (size_t)(n0 + n_l) * 1024 + c0 + b_l * 16;
  *(ushort8*)(ho)     = h0;
  *(ushort8*)(ho + 8) = h1;
  __syncthreads();

  for (int i = threadIdx.x; i < 512; i += 256) {
    int row = i >> 3, ch = i & 7;
    const unsigned short* s = ht + row * 72 + ch * 8;
    int2 v;
    v.x = pk4_fp8(bf2f(s[0]), bf2f(s[1]), bf2f(s[2]), bf2f(s[3]));
    v.y = pk4_fp8(bf2f(s[4]), bf2f(s[5]), bf2f(s[6]), bf2f(s[7]));
    *(int2*)(hb8 + (size_t)(c0 + row) * 4096 + n0 + ch * 8) = v;
  }
}

// ---------------------------------------------------------------------------
// final: out fp32 (b,n,d) = p0 + p1 + h_nc   (all stored [n][c] bf16)
// ---------------------------------------------------------------------------
__global__ void add_out(const unsigned short* __restrict__ pp,
                        const unsigned short* __restrict__ hnc,
                        float* __restrict__ out) {
  int gid = blockIdx.x * 256 + threadIdx.x;      // 0..524287
  int n = gid >> 7, c8 = (gid & 127) * 8;
  size_t g = (size_t)n * 1024 + c8;
  ushort8 a = *(const ushort8*)(pp + g);
  ushort8 b = *(const ushort8*)(pp + P_ELEMS + g);
  ushort8 h = *(const ushort8*)(hnc + g);
  float v[8];
#pragma unroll
  for (int j = 0; j < 8; ++j) v[j] = bf2f(a[j]) + bf2f(b[j]) + bf2f(h[j]);
  int bb = c8 >> 4, d0 = c8 & 15;                // d0 = 0 or 8
  float* o = out + (size_t)bb * 65536 + n * 16 + d0;
  *(float4*)(o)     = float4{v[0], v[1], v[2], v[3]};
  *(float4*)(o + 4) = float4{v[4], v[5], v[6], v[7]};
}

// ---------------------------------------------------------------------------
// p[ks][n][c] = (adj8[n0..][k] * hb8[c0..][k]) / 4096   (one K-half per block)
// MX-scaled fp8 MFMA 16x16x128, unit scales.  Grid 512 = 32mt x 8ct x 2ks,
// xcd = mt&7 (all 8 ct-consumers of an adj8 slice land on one XCD -> L2
// reuse), 4 waves 2x2, wave tile 64x64.
// K-loop (T3+T4): dbuf, counted s_waitcnt vmcnt(8) + raw s_barrier.
//   prologue: STAGE(0), STAGE(1)            [16 loads in flight]
//   iter it:  vmcnt(8)  -> stage(it) done, stage(it+1) still flying
//             s_barrier -> all waves' stage(it) visible
//             COMPUTE(it)  [setprio(1) around MFMA cluster]
//             s_barrier -> all waves done reading buf
//             STAGE(it+2) into the buf just freed
// Load latency (~900cyc) drains 2 iters after issue, under compute + the
// co-resident block.  No vmcnt(0) in the main loop.
// ---------------------------------------------------------------------------
__global__ __launch_bounds__(256, 2)
void gemm_f8(const unsigned char* __restrict__ A,
             const unsigned char* __restrict__ B8,
             unsigned short* __restrict__ pp) {
  const int K = 4096;
  __shared__ unsigned char a_s[2][128 * 128];   // 2 x 16 KB
  __shared__ unsigned char b_s[2][128 * 128];   // 2 x 16 KB

  int tid = threadIdx.x, wave = tid >> 6, lane = tid & 63;

  int lin = blockIdx.x;
  int xcd = lin & 7, g = lin >> 3;
  int mth = g & 3, ct = (g >> 2) & 7, ks = g >> 5;   // ks in {0,1}
  int mt = mth * 8 + xcd;
  int n0 = mt * 128, c0 = ct * 128;
  int kbase = ks * 2048;

  // staging: wave w covers rows w*32..w*32+31 (4 insts each operand)
  int l8 = lane >> 3, lc = lane & 7;
  int swc = lc ^ l8;                 // logical chunk fetched into phys lc
  const unsigned char* gA[4];
  const unsigned char* gB[4];
#pragma unroll
  for (int j = 0; j < 4; ++j) {
    int r = wave * 32 + j * 8 + l8;
    gA[j] = A  + (size_t)(n0 + r) * K + kbase + swc * 16;
    gB[j] = B8 + (size_t)(c0 + r) * K + kbase + swc * 16;
  }

  int i16 = lane & 15, q = lane >> 4;
  int wm = wave >> 1, wn = wave & 1;
  int sw7 = i16 & 7;
  int pc0 = ((2 * q) ^ sw7) * 16;        // phys offset of logical chunk 2q
  int pc1 = ((2 * q + 1) ^ sw7) * 16;    // phys offset of logical chunk 2q+1

#define STAGE(buf, it)                                                \
  do {                                                                \
    int k0_ = (it) * 128;                                             \
    _Pragma("unroll")                                                 \
    for (int j = 0; j < 4; ++j) {                                     \
      GLOAD_LDS16(gA[j] + k0_, a_s[buf] + (wave * 32 + j * 8) * 128); \
      GLOAD_LDS16(gB[j] + k0_, b_s[buf] + (wave * 32 + j * 8) * 128); \
    }                                                                 \
  } while (0)

#define COMPUTE(buf)                                                  \
  do {                                                                \
    i32x8 bv[4];                                                      \
    _Pragma("unroll")                                                 \
    for (int u = 0; u < 4; ++u) {                                     \
      const unsigned char* bp = b_s[buf] + (wn * 64 + u * 16 + i16) * 128; \
      i32x4 blo = *(const i32x4*)(bp + pc0);                          \
      i32x4 bhi = *(const i32x4*)(bp + pc1);                          \
      bv[u] = __builtin_shufflevector(blo, bhi, 0, 1, 2, 3, 4, 5, 6, 7); \
    }                                                                 \
    __builtin_amdgcn_s_setprio(1);                                    \
    _Pragma("unroll")                                                 \
    for (int t = 0; t < 4; ++t) {                                     \
      const unsigned char* ap = a_s[buf] + (wm * 64 + t * 16 + i16) * 128; \
      i32x4 alo = *(const i32x4*)(ap + pc0);                          \
      i32x4 ahi = *(const i32x4*)(ap + pc1);                          \
      i32x8 av = __builtin_shufflevector(alo, ahi, 0, 1, 2, 3, 4, 5, 6, 7); \
      _Pragma("unroll")                                               \
      for (int u = 0; u < 4; ++u)                                     \
        acc[t][u] = __builtin_amdgcn_mfma_scale_f32_16x16x128_f8f6f4( \
            av, bv[u], acc[t][u], 0, 0, 0, SCALE_ONE, 0, SCALE_ONE);  \
    }                                                                 \
    __builtin_amdgcn_s_setprio(0);                                    \
  } while (0)

#define WAITVM8() asm volatile("s_waitcnt vmcnt(8)" ::: "memory")
#define WAITVM0() asm volatile("s_waitcnt vmcnt(0)" ::: "memory")
#define BARX() do { asm volatile("" ::: "memory");                    \
                    __builtin_amdgcn_s_barrier();                     \
                    asm volatile("" ::: "memory"); } while (0)

  f32x4 acc[4][4] = {};

  // prologue: two tiles in flight
  STAGE(0, 0);
  STAGE(1, 1);

  for (int itb = 0; itb < 14; itb += 2) {
    WAITVM8(); BARX(); COMPUTE(0); BARX(); STAGE(0, itb + 2);
    WAITVM8(); BARX(); COMPUTE(1); BARX(); STAGE(1, itb + 3);
  }
  WAITVM8(); BARX(); COMPUTE(0);           // it = 14 (stage15 still flying)
  WAITVM0(); BARX(); COMPUTE(1);           // it = 15

#undef STAGE
#undef COMPUTE
#undef WAITVM8
#undef WAITVM0
#undef BARX

  // epilogue: descale + bf16 store of this K-half's partial
  unsigned short* dst = pp + (size_t)ks * P_ELEMS;
#pragma unroll
  for (int t = 0; t < 4; ++t)
#pragma unroll
    for (int u = 0; u < 4; ++u)
#pragma unroll
      for (int i = 0; i < 4; ++i) {
        int n_g = n0 + wm * 64 + t * 16 + q * 4 + i;
        int c_g = c0 + wn * 64 + u * 16 + i16;
        dst[(size_t)n_g * 1024 + c_g] = f2bf(acc[t][u][i] * ADJ_DESCALE);
      }
}

// ---------------------------------------------------------------------------
extern "C" void kernel_launch(void* const* d_in, const int* in_sizes, int n_in,
                              void* d_out, int out_size, void* d_ws, size_t ws_size,
                              hipStream_t stream) {
  const float* x   = (const float*)d_in[0];
  const float* adj = (const float*)d_in[1];
  // d_in[2] = Identity (handled as the +h_nc term)
  const float* W0  = (const float*)d_in[3];
  const float* W1  = (const float*)d_in[4];
  const float* W2  = (const float*)d_in[5];
  float* out = (float*)d_out;

  char* ws = (char*)d_ws;
  unsigned char*  adj8 = (unsigned char*)ws;                   // 16 MiB
  unsigned char*  hb8  = (unsigned char*)(ws + 16777216);      //  4 MiB
  unsigned short* hnc  = (unsigned short*)(ws + 20971520);     //  8 MiB
  unsigned short* pp   = (unsigned short*)(ws + 29360128);     // p0|p1 16 MiB

  // layer 0 linear + adj quantize fused (independent, both memory-bound)
  prep<<<5120, 256, 0, stream>>>(adj, adj8, x, W0, hb8, hnc);
  gemm_f8<<<512, 256, 0, stream>>>(adj8, hb8, pp);
  // layer 1
  linear_fuse<<<dim3(64, 16), 256, 0, stream>>>(pp, hnc, W1, hb8, hnc);
  gemm_f8<<<512, 256, 0, stream>>>(adj8, hb8, pp);
  // layer 2
  linear_fuse<<<dim3(64, 16), 256, 0, stream>>>(pp, hnc, W2, hb8, hnc);
  gemm_f8<<<512, 256, 0, stream>>>(adj8, hb8, pp);
  add_out<<<2048, 256, 0, stream>>>(pp, hnc, out);
}